// Round 8
// baseline (157.514 us; speedup 1.0000x reference)
//
#include <hip/hip_runtime.h>

#define NFULL 128
#define NOUT  122
#define NBLK  1040   // 4 batch x 4 wtile x 13 htile x 5 dchunk

// DPP row_shl:k — lane i reads lane i+k within its 16-lane row (bound_ctrl -> 0)
template<int CTRL>
__device__ __forceinline__ float dppshl(float v) {
    return __int_as_float(
        __builtin_amdgcn_update_dpp(0, __float_as_int(v), CTRL, 0xF, 0xF, true));
}

__global__ __launch_bounds__(256, 4)
void ssim3d_kernel(const float* __restrict__ X, const float* __restrict__ Y,
                   const float* __restrict__ DR, double* __restrict__ wsout, int mode)
{
    __shared__ float sm[4];

    const int tid  = threadIdx.x;
    const int wave = tid >> 6;
    const int lane = tid & 63;
    const int h = lane & 15;       // row-in-tile 0..15 (low bits => DPP row)
    const int c = lane >> 4;       // colpair 0..3

    int bi = blockIdx.x;
    const int bb = bi & 3;  bi >>= 2;   // batch
    const int wt = bi & 3;  bi >>= 2;   // 4 w-tiles of 32
    const int ht = bi % 13;             // 13 h-tiles of 10
    const int dc = bi / 13;             // 5 d-chunks

    const int hb = ht * 10;
    int grow = hb + h; if (grow > NFULL - 1) grow = NFULL - 1;
    const int wbase = wt * 32 + wave * 8;
    int colb = wbase + 2 * c; if (colb > NFULL - 8) colb = NFULL - 8;
    const int csize = (dc < 2) ? 25 : 24;
    const int d0 = (dc < 2) ? 25 * dc : 50 + (dc - 2) * 24;
    const int nsl = csize + 6;          // slices d0..d0+nsl-1 (max 127)

    // SSIM constants scaled by 343^2 (ratio-invariant; validated R4-R7)
    const float dr  = DR[bb];
    const float c1s = (0.01f * dr) * (0.01f * dr) * 117649.0f;
    const float c2s = (0.03f * dr) * (0.03f * dr) * 117649.0f;
    const float tni = 1.0f / 343.0f;
    const float kkA = 2.0f * 117649.0f / 342.0f;
    const float kkB = 117649.0f / 342.0f;

    const int gh  = hb + h;
    const int gw0 = wbase + 2 * c;
    const bool vh   = (h < 10) && (gh < NOUT);
    const bool vld0 = vh && (gw0 < NOUT);
    const bool vld1 = vh && (gw0 + 1 < NOUT);

    const size_t planeStride = (size_t)NFULL * NFULL;
    const size_t rowoff = (size_t)bb * NFULL * planeStride
                        + (size_t)grow * NFULL + colb
                        + (size_t)d0 * planeStride;

    // ring/run over 10 components: [2q+j], j = output column 0/1
    float ring[7][10];
    float run[10];
#pragma unroll
    for (int k = 0; k < 7; ++k)
#pragma unroll
        for (int q = 0; q < 10; ++q) ring[k][q] = 0.f;
#pragma unroll
    for (int q = 0; q < 10; ++q) run[q] = 0.f;
    float acc = 0.0f;

    // Main loop: NO LDS, NO barriers. W-sums in regs, H-sums via DPP, D-ring in regs.
    for (int base = 0; base < nsl; base += 7) {
#pragma unroll
        for (int u = 0; u < 7; ++u) {
            const int s = base + u;
            if (s < nsl) {
                const float* px = X + rowoff + (size_t)s * planeStride;
                const float* py = Y + rowoff + (size_t)s * planeStride;

                // ---- W-sums: strip of 8 -> 2 outputs x 5 products ----
                float xs[8], ys[8];
#pragma unroll
                for (int k = 0; k < 4; ++k) {
                    float2 tx = *(const float2*)(px + 2 * k);
                    float2 ty = *(const float2*)(py + 2 * k);
                    xs[2 * k] = tx.x; xs[2 * k + 1] = tx.y;
                    ys[2 * k] = ty.x; ys[2 * k + 1] = ty.y;
                }
                float f[10];
                {
                    float sx = 0.f, sy = 0.f, sxx = 0.f, syy = 0.f, sxy = 0.f;
#pragma unroll
                    for (int k = 0; k < 7; ++k) {
                        sx += xs[k]; sy += ys[k];
                        sxx = fmaf(xs[k], xs[k], sxx);
                        syy = fmaf(ys[k], ys[k], syy);
                        sxy = fmaf(xs[k], ys[k], sxy);
                    }
                    f[0] = sx;  f[1] = sx - xs[0] + xs[7];
                    f[2] = sy;  f[3] = sy - ys[0] + ys[7];
                    f[4] = sxx; f[5] = sxx - xs[0] * xs[0] + xs[7] * xs[7];
                    f[6] = syy; f[7] = syy - ys[0] * ys[0] + ys[7] * ys[7];
                    f[8] = sxy; f[9] = sxy - xs[0] * ys[0] + xs[7] * ys[7];
                }

                // ---- H-sums: 7-tap across lanes h..h+6 via DPP row_shl tree ----
                // t1 = v[h]+v[h+1]; t2 = t1+t1[h+2] (4-sum); t3 = t2+t1[h+4] (6-sum);
                // g  = t3+v[h+6] (7-sum). Valid for h<=9 (in-row).
                const int slot = u;    // s % 7, static after unroll
#pragma unroll
                for (int q = 0; q < 10; ++q) {
                    float v  = f[q];
                    float t1 = v  + dppshl<0x101>(v);
                    float t2 = t1 + dppshl<0x102>(t1);
                    float t3 = t2 + dppshl<0x104>(t1);
                    float g  = t3 + dppshl<0x106>(v);
                    run[q] += g - ring[slot][q];
                    ring[slot][q] = g;
                }

                // ---- SSIM for 2 outputs ----
                if (s >= 6) {
#pragma unroll
                    for (int j = 0; j < 2; ++j) {
                        const bool vld = j ? vld1 : vld0;
                        if (vld) {
                            float Sx  = run[0 + j];
                            float Sy  = run[2 + j];
                            float Sxx = run[4 + j];
                            float Syy = run[6 + j];
                            float Sxy = run[8 + j];
                            float P = Sx * Sy;
                            float Q = fmaf(Sx, Sx, Sy * Sy);
                            float A1 = fmaf(2.f, P, c1s);
                            float A2 = fmaf(kkA, fmaf(-tni, P, Sxy), c2s);
                            float B1 = Q + c1s;
                            float B2 = fmaf(kkB, fmaf(-tni, Q, Sxx + Syy), c2s);
                            float num = A1 * A2;
                            float den = B1 * B2;
                            float r0 = __builtin_amdgcn_rcpf(den);
                            r0 = r0 * fmaf(-den, r0, 2.0f);   // 1 Newton step
                            acc = fmaf(num, r0, acc);
                        }
                    }
                }
            }
        }
    }

    // ---- reduction: wave shuffle -> LDS -> per-block partial (double) ----
#pragma unroll
    for (int off = 32; off; off >>= 1) acc += __shfl_down(acc, off);
    if (lane == 0) sm[wave] = acc;
    __syncthreads();
    if (tid == 0) {
        double t = (double)sm[0] + (double)sm[1] + (double)sm[2] + (double)sm[3];
        if (mode) wsout[blockIdx.x] = t;
        else      atomicAdd(wsout, t);
    }
}

__global__ void ssim3d_finalize(const double* __restrict__ ws, float* __restrict__ out, int mode)
{
    if (mode) {
        __shared__ double sm[4];
        const int tid = threadIdx.x;
        double t = 0.0;
        for (int i = tid; i < NBLK; i += 256) t += ws[i];
#pragma unroll
        for (int off = 32; off; off >>= 1) t += __shfl_down(t, off);
        if ((tid & 63) == 0) sm[tid >> 6] = t;
        __syncthreads();
        if (tid == 0) {
            double r = sm[0] + sm[1] + sm[2] + sm[3];
            out[0] = (float)(r * (1.0 / 7263392.0));   // 4 * 122^3
        }
    } else {
        if (threadIdx.x == 0)
            out[0] = (float)(ws[0] * (1.0 / 7263392.0));
    }
}

extern "C" void kernel_launch(void* const* d_in, const int* in_sizes, int n_in,
                              void* d_out, int out_size, void* d_ws, size_t ws_size,
                              hipStream_t stream)
{
    const float* X  = (const float*)d_in[0];
    const float* Y  = (const float*)d_in[1];
    const float* DR = (const float*)d_in[2];
    double* ws = (double*)d_ws;

    const int mode = (ws_size >= NBLK * sizeof(double)) ? 1 : 0;
    if (!mode) hipMemsetAsync(d_ws, 0, sizeof(double), stream);
    ssim3d_kernel<<<NBLK, 256, 0, stream>>>(X, Y, DR, ws, mode);
    ssim3d_finalize<<<1, 256, 0, stream>>>(ws, (float*)d_out, mode);
}